// Round 1
// baseline (874.495 us; speedup 1.0000x reference)
//
#include <hip/hip_runtime.h>
#include <hip/hip_bf16.h>
#include <cstdint>
#include <cstddef>

#define NH   16
#define DHD  64
#define DM   1024
#define BSZ  8
#define SEQ  4096
#define NTOK (BSZ*SEQ)      // 32768 tokens
#define NQKV (3*NH*DHD)     // 3072

typedef __attribute__((ext_vector_type(8))) __bf16 bf16x8;
typedef __attribute__((ext_vector_type(4))) float  floatx4;

// ---- helpers ----
static __device__ __forceinline__ unsigned short f2bf(float f) {
    unsigned int u = __float_as_uint(f);
    u += 0x7fffu + ((u >> 16) & 1u);   // RNE
    return (unsigned short)(u >> 16);
}
static __device__ __forceinline__ float bf2f(unsigned int us) {
    return __uint_as_float(us << 16);
}
static __device__ __forceinline__ void load_lds16(const void* g, void* l) {
    __builtin_amdgcn_global_load_lds((__attribute__((address_space(1))) void*)g,
                                     (__attribute__((address_space(3))) void*)l,
                                     16, 0, 0);
}

// ---- cast fp32 -> bf16 (vectorized, exact multiple of 4) ----
__global__ __launch_bounds__(256) void k_cast_bf16(const float* __restrict__ in,
                                                   unsigned short* __restrict__ out, int n4) {
    int i = blockIdx.x * 256 + threadIdx.x;
    if (i >= n4) return;
    float4 v = ((const float4*)in)[i];
    ushort4 o;
    o.x = f2bf(v.x); o.y = f2bf(v.y); o.z = f2bf(v.z); o.w = f2bf(v.w);
    ((ushort4*)out)[i] = o;
}

// ---- transpose + cast: in fp32 [R][C] -> out bf16 [C][R] ----
template<int R, int C>
__global__ __launch_bounds__(256) void k_transpose_cast(const float* __restrict__ in,
                                                        unsigned short* __restrict__ out) {
    __shared__ float tile[32][33];
    int tx = threadIdx.x, ty = threadIdx.y;    // (32, 8)
    int col = blockIdx.x * 32 + tx;
#pragma unroll
    for (int k = 0; k < 4; k++) {
        int row = blockIdx.y * 32 + ty + k * 8;
        tile[ty + k * 8][tx] = in[(size_t)row * C + col];
    }
    __syncthreads();
#pragma unroll
    for (int k = 0; k < 4; k++) {
        int ocol = blockIdx.x * 32 + ty + k * 8;   // original col -> out row
        int orow = blockIdx.y * 32 + tx;           // original row -> out col
        out[(size_t)ocol * R + orow] = f2bf(tile[tx][ty + k * 8]);
    }
}

// ---- positional encoding table fp32 [4096][64] ----
__global__ __launch_bounds__(256) void k_pe(float* __restrict__ pe) {
    int t = blockIdx.x * 256 + threadIdx.x;   // 4096*32
    int l = t >> 5, i = t & 31;
    float dv = expf(-0.14391156831212787f * (float)(2 * i));
    float ang = (float)l * dv;
    pe[l * 64 + 2 * i]     = sinf(ang);
    pe[l * 64 + 2 * i + 1] = cosf(ang);
}

// ============================================================================
// 256x256-tile 8-phase bf16 GEMM (HK-style schedule), K = 1024, BK = 64.
//   C[M][N] = A[M][K] @ BT[N][K]^T + bias, with optional qkv epilogue.
// 8 waves as 2(M) x 4(N); per-wave output 128x64 = acc[8][4] of 16x16 frags.
// LDS 128 KiB: A[2 dbuf][256][64], B[2 dbuf][256][64] bf16, XOR-swizzled:
//   physical 16B-slot s of row r holds logical slot s ^ (r&7)  (bank-conflict-free
//   ds_read_b128; realized by pre-swizzling the *global* source per lane since
//   global_load_lds writes linearly).
// Per iteration (2 K-tiles, ktA=buf0 even, ktB=buf1 odd), 8 phases:
//   ph1: read ktA m0-3 (both k-halves) + B kh0  [12 ds_read]; stage ktB.A1; MFMA(m0-3,kh0)
//   ph2: read ktA m4-7 (both)         + B kh1  [12 ds_read]; stage ktB.B1; MFMA(m0-3,kh1)
//   ph3:                                    stage ktA+2.A0;               MFMA(m4-7,kh0)
//   ph4:                                    stage ktA+2.B0; vmcnt(4);     MFMA(m4-7,kh1)
//   ph5-8: same for ktB (buf1), staging ktA+2.A1/B1, ktB+2.A0/B0; vmcnt(4) at ph8.
// Front-loaded reads free buf0 after ph2 / buf1 after ph6, which is what makes
// staging kt+2 legal from ph3/ph7. vmcnt(4) = 2 half-tiles in flight; derived
// safe for this schedule (vmcnt(0) only in the last iteration's ph4).
// ============================================================================
template<int N, int EPI>
__global__ __launch_bounds__(512, 2) void k_gemm8(const unsigned short* __restrict__ A,
                                                  const unsigned short* __restrict__ BT,
                                                  const float* __restrict__ bias,
                                                  const float* __restrict__ pe,
                                                  void* __restrict__ Cout) {
    constexpr int K   = 1024;
    constexpr int NKT = K / 64;          // 16 K-tiles
    constexpr int NIT = NKT / 2;         // 8 iterations
    constexpr int NBX = N / 256;
    constexpr int nwg = NBX * (NTOK / 256);

    __shared__ __align__(16) short sh[65536];   // 128 KiB
    char* shb = (char*)sh;
    // byte layout: A buf b @ b*32768 ; B buf b @ 65536 + b*32768

    const int tid  = threadIdx.x;
    const int lane = tid & 63;
    const int wid  = tid >> 6;
    const int l15  = lane & 15;
    const int q4   = lane >> 4;
    const int wr   = wid >> 2;           // 0..1 (M)
    const int wc   = wid & 3;            // 0..3 (N)

    // XCD-aware block swizzle (nwg % 8 == 0 for both GEMMs)
    const int id = blockIdx.x;
    const int sw = (id & 7) * (nwg >> 3) + (id >> 3);
    const int m0 = (sw / NBX) * 256;
    const int n0 = (sw % NBX) * 256;

    // ---- staging setup: thread stages 2 chunks (16B) per matrix per half-tile ----
    int cj[2];
    const unsigned short* srcA[2];
    const unsigned short* srcB[2];
#pragma unroll
    for (int j = 0; j < 2; j++) {
        int c  = wid * 128 + j * 64 + lane;    // physical chunk in half-tile, 0..1023
        cj[j]  = c;
        int rh = c >> 3;                        // row within half (0..127)
        int sl = (c & 7) ^ (rh & 7);            // logical 16B slot (inverse swizzle)
        srcA[j] = A  + (size_t)(m0 + rh) * K + sl * 8;
        srcB[j] = BT + (size_t)(n0 + rh) * K + sl * 8;
    }
    auto STAGE_A = [&](int kt, int half) {
#pragma unroll
        for (int j = 0; j < 2; j++)
            load_lds16(srcA[j] + half * 128 * K + kt * 64,
                       shb + (kt & 1) * 32768 + half * 16384 + cj[j] * 16);
    };
    auto STAGE_B = [&](int kt, int half) {
#pragma unroll
        for (int j = 0; j < 2; j++)
            load_lds16(srcB[j] + half * 128 * K + kt * 64,
                       shb + 65536 + (kt & 1) * 32768 + half * 16384 + cj[j] * 16);
    };

    // ---- fragment read addressing (swizzled) ----
    const int swz  = (l15 & 7) << 4;
    const int cb0  = ((q4 * 16) ^ swz);            // k-half 0 byte col
    const int cb1  = ((64 + q4 * 16) ^ swz);       // k-half 1 byte col
    const int rowA = (wr * 128 + l15) * 128;       // byte row base, A side
    const int rowB = (wc * 64  + l15) * 128;       // byte row base, B side
    auto RDA = [&](int b, int i, int cb) -> bf16x8 {
        return *(const bf16x8*)(shb + b * 32768 + rowA + i * 2048 + cb);
    };
    auto RDB = [&](int b, int n, int cb) -> bf16x8 {
        return *(const bf16x8*)(shb + 65536 + b * 32768 + rowB + n * 2048 + cb);
    };

    floatx4 acc[8][4];
#pragma unroll
    for (int i = 0; i < 8; i++)
#pragma unroll
        for (int n = 0; n < 4; n++) acc[i][n] = (floatx4){0.f, 0.f, 0.f, 0.f};

    bf16x8 aF0[4][2], aF1[4][2], bF[4][2];

    // ---- prologue: kt0 fully + kt1 first halves; leave 2 half-tiles in flight ----
    STAGE_A(0, 0); STAGE_B(0, 0); STAGE_A(0, 1); STAGE_B(0, 1);
    STAGE_A(1, 0); STAGE_B(1, 0);
    asm volatile("s_waitcnt vmcnt(4)" ::: "memory");   // kt0 complete
    __builtin_amdgcn_s_barrier();

#pragma unroll 1
    for (int it = 0; it < NIT; ++it) {
        const int kB = 2 * it + 1;
        const bool more = (it < NIT - 1);

        // -------- phase 1
#pragma unroll
        for (int i = 0; i < 4; i++) { aF0[i][0] = RDA(0, i, cb0); aF0[i][1] = RDA(0, i, cb1); }
#pragma unroll
        for (int n = 0; n < 4; n++) bF[n][0] = RDB(0, n, cb0);
        STAGE_A(kB, 1);
        __builtin_amdgcn_s_barrier();
        asm volatile("s_waitcnt lgkmcnt(0)" ::: "memory");
        __builtin_amdgcn_s_setprio(1);
#pragma unroll
        for (int i = 0; i < 4; i++)
#pragma unroll
            for (int n = 0; n < 4; n++)
                acc[i][n] = __builtin_amdgcn_mfma_f32_16x16x32_bf16(aF0[i][0], bF[n][0], acc[i][n], 0, 0, 0);
        __builtin_amdgcn_s_setprio(0);
        __builtin_amdgcn_s_barrier();

        // -------- phase 2
#pragma unroll
        for (int i = 0; i < 4; i++) { aF1[i][0] = RDA(0, i + 4, cb0); aF1[i][1] = RDA(0, i + 4, cb1); }
#pragma unroll
        for (int n = 0; n < 4; n++) bF[n][1] = RDB(0, n, cb1);
        STAGE_B(kB, 1);
        __builtin_amdgcn_s_barrier();
        asm volatile("s_waitcnt lgkmcnt(0)" ::: "memory");
        __builtin_amdgcn_s_setprio(1);
#pragma unroll
        for (int i = 0; i < 4; i++)
#pragma unroll
            for (int n = 0; n < 4; n++)
                acc[i][n] = __builtin_amdgcn_mfma_f32_16x16x32_bf16(aF0[i][1], bF[n][1], acc[i][n], 0, 0, 0);
        __builtin_amdgcn_s_setprio(0);
        __builtin_amdgcn_s_barrier();

        // -------- phase 3 (buf0 read-free from here)
        if (more) STAGE_A(kB + 1, 0);
        __builtin_amdgcn_s_barrier();
        __builtin_amdgcn_s_setprio(1);
#pragma unroll
        for (int i = 0; i < 4; i++)
#pragma unroll
            for (int n = 0; n < 4; n++)
                acc[i + 4][n] = __builtin_amdgcn_mfma_f32_16x16x32_bf16(aF1[i][0], bF[n][0], acc[i + 4][n], 0, 0, 0);
        __builtin_amdgcn_s_setprio(0);
        __builtin_amdgcn_s_barrier();

        // -------- phase 4
        if (more) STAGE_B(kB + 1, 0);
        if (more) asm volatile("s_waitcnt vmcnt(4)" ::: "memory");   // ktB fully staged
        else      asm volatile("s_waitcnt vmcnt(0)" ::: "memory");
        __builtin_amdgcn_s_barrier();
        __builtin_amdgcn_s_setprio(1);
#pragma unroll
        for (int i = 0; i < 4; i++)
#pragma unroll
            for (int n = 0; n < 4; n++)
                acc[i + 4][n] = __builtin_amdgcn_mfma_f32_16x16x32_bf16(aF1[i][1], bF[n][1], acc[i + 4][n], 0, 0, 0);
        __builtin_amdgcn_s_setprio(0);
        __builtin_amdgcn_s_barrier();

        // -------- phase 5 (ktB in buf1)
#pragma unroll
        for (int i = 0; i < 4; i++) { aF0[i][0] = RDA(1, i, cb0); aF0[i][1] = RDA(1, i, cb1); }
#pragma unroll
        for (int n = 0; n < 4; n++) bF[n][0] = RDB(1, n, cb0);
        if (more) STAGE_A(kB + 1, 1);
        __builtin_amdgcn_s_barrier();
        asm volatile("s_waitcnt lgkmcnt(0)" ::: "memory");
        __builtin_amdgcn_s_setprio(1);
#pragma unroll
        for (int i = 0; i < 4; i++)
#pragma unroll
            for (int n = 0; n < 4; n++)
                acc[i][n] = __builtin_amdgcn_mfma_f32_16x16x32_bf16(aF0[i][0], bF[n][0], acc[i][n], 0, 0, 0);
        __builtin_amdgcn_s_setprio(0);
        __builtin_amdgcn_s_barrier();

        // -------- phase 6
#pragma unroll
        for (int i = 0; i < 4; i++) { aF1[i][0] = RDA(1, i + 4, cb0); aF1[i][1] = RDA(1, i + 4, cb1); }
#pragma unroll
        for (int n = 0; n < 4; n++) bF[n][1] = RDB(1, n, cb1);
        if (more) STAGE_B(kB + 1, 1);
        __builtin_amdgcn_s_barrier();
        asm volatile("s_waitcnt lgkmcnt(0)" ::: "memory");
        __builtin_amdgcn_s_setprio(1);
#pragma unroll
        for (int i = 0; i < 4; i++)
#pragma unroll
            for (int n = 0; n < 4; n++)
                acc[i][n] = __builtin_amdgcn_mfma_f32_16x16x32_bf16(aF0[i][1], bF[n][1], acc[i][n], 0, 0, 0);
        __builtin_amdgcn_s_setprio(0);
        __builtin_amdgcn_s_barrier();

        // -------- phase 7 (buf1 read-free from here)
        if (more) STAGE_A(kB + 2, 0);
        __builtin_amdgcn_s_barrier();
        __builtin_amdgcn_s_setprio(1);
#pragma unroll
        for (int i = 0; i < 4; i++)
#pragma unroll
            for (int n = 0; n < 4; n++)
                acc[i + 4][n] = __builtin_amdgcn_mfma_f32_16x16x32_bf16(aF1[i][0], bF[n][0], acc[i + 4][n], 0, 0, 0);
        __builtin_amdgcn_s_setprio(0);
        __builtin_amdgcn_s_barrier();

        // -------- phase 8
        if (more) STAGE_B(kB + 2, 0);
        if (more) asm volatile("s_waitcnt vmcnt(4)" ::: "memory");   // next ktA fully staged
        __builtin_amdgcn_s_barrier();
        __builtin_amdgcn_s_setprio(1);
#pragma unroll
        for (int i = 0; i < 4; i++)
#pragma unroll
            for (int n = 0; n < 4; n++)
                acc[i + 4][n] = __builtin_amdgcn_mfma_f32_16x16x32_bf16(aF1[i][1], bF[n][1], acc[i + 4][n], 0, 0, 0);
        __builtin_amdgcn_s_setprio(0);
        __builtin_amdgcn_s_barrier();
    }

    // ---- epilogue: repack through LDS (per-wave region), coalesced stores ----
    // wave region: 32 rows x 68 f32 (stride 68 keeps float4 alignment + spreads banks)
    float* X = (float*)shb + wid * 2176;
#pragma unroll
    for (int cidx = 0; cidx < 4; ++cidx) {        // 4 chunks of 2 m-frags (32 rows)
#pragma unroll
        for (int i2 = 0; i2 < 2; ++i2) {
            const int i = cidx * 2 + i2;
#pragma unroll
            for (int n = 0; n < 4; ++n) {
                const int col = n0 + wc * 64 + n * 16 + l15;
                const float bv = bias[col];
                int rc = 0;
                if (EPI == 1) { int h = col / 192; rc = col - h * 192; }
#pragma unroll
                for (int r = 0; r < 4; ++r) {
                    const int lrow = i2 * 16 + q4 * 4 + r;
                    float v = acc[i][n][r] + bv;
                    if (EPI == 1) {
                        const int grow = m0 + wr * 128 + cidx * 32 + lrow;
                        if (rc < 64)        v *= 0.125f;                    // q * (1/sqrt(64))
                        else if (rc < 128)  v += pe[(grow & (SEQ - 1)) * 64 + (rc - 64)];
                    }
                    X[lrow * 68 + n * 16 + l15] = v;
                }
            }
        }
#pragma unroll
        for (int rr = 0; rr < 8; ++rr) {
            const int lr   = rr * 4 + q4;
            const int grow = m0 + wr * 128 + cidx * 32 + lr;
            const float* p = X + lr * 68 + l15 * 4;
            if (EPI == 1) {
                ushort4 o;
                o.x = f2bf(p[0]); o.y = f2bf(p[1]); o.z = f2bf(p[2]); o.w = f2bf(p[3]);
                *(ushort4*)((unsigned short*)Cout + (size_t)grow * N + n0 + wc * 64 + l15 * 4) = o;
            } else {
                float4 o = make_float4(p[0], p[1], p[2], p[3]);
                *(float4*)((float*)Cout + (size_t)grow * N + n0 + wc * 64 + l15 * 4) = o;
            }
        }
    }
}

// ---- per-token across-heads attention: 1 wave per token ----
// qkv row layout: head h -> [q(64) | k(64) | v(64)] at col h*192; q pre-scaled, k has pe.
__global__ __launch_bounds__(256) void k_attn(const unsigned short* __restrict__ qkv,
                                              unsigned short* __restrict__ aout) {
    __shared__ __align__(16) float X4[4][3264];   // per-wave: 16 rows, stride 204
    __shared__ float S4[4][272];                  // softmax probs, [16][17]
    int tid = threadIdx.x, wid = tid >> 6, lane = tid & 63;
    int t = blockIdx.x * 4 + wid;

    float* X = X4[wid];
    const unsigned short* src = qkv + (size_t)t * NQKV;

#pragma unroll
    for (int c = 0; c < 6; c++) {
        int ci = c * 64 + lane;
        uint4 u = ((const uint4*)src)[ci];
        int j0 = ci * 8;
        int h  = j0 / 192;
        int rc = j0 - h * 192;
        float* dst = X + h * 204 + rc;
        floatx4 f0 = { bf2f(u.x & 0xffff), bf2f(u.x >> 16), bf2f(u.y & 0xffff), bf2f(u.y >> 16) };
        floatx4 f1 = { bf2f(u.z & 0xffff), bf2f(u.z >> 16), bf2f(u.w & 0xffff), bf2f(u.w >> 16) };
        *(floatx4*)dst       = f0;
        *(floatx4*)(dst + 4) = f1;
    }
    __syncthreads();

    int h  = lane >> 2;
    int g0 = (lane & 3) * 4;
    const float* Q = X + h * 204;
    float s0 = 0.f, s1 = 0.f, s2 = 0.f, s3 = 0.f;
#pragma unroll 8
    for (int d = 0; d < 64; d++) {
        float qd = Q[d];
        s0 += qd * X[(g0 + 0) * 204 + 64 + d];
        s1 += qd * X[(g0 + 1) * 204 + 64 + d];
        s2 += qd * X[(g0 + 2) * 204 + 64 + d];
        s3 += qd * X[(g0 + 3) * 204 + 64 + d];
    }
    float mx = fmaxf(fmaxf(s0, s1), fmaxf(s2, s3));
    mx = fmaxf(mx, __shfl_xor(mx, 1));
    mx = fmaxf(mx, __shfl_xor(mx, 2));
    float e0 = __expf(s0 - mx), e1 = __expf(s1 - mx), e2 = __expf(s2 - mx), e3 = __expf(s3 - mx);
    float sum = e0 + e1 + e2 + e3;
    sum += __shfl_xor(sum, 1);
    sum += __shfl_xor(sum, 2);
    float inv = 1.0f / sum;
    float* Sr = &S4[wid][h * 17];
    Sr[g0 + 0] = e0 * inv; Sr[g0 + 1] = e1 * inv; Sr[g0 + 2] = e2 * inv; Sr[g0 + 3] = e3 * inv;
    __syncthreads();

    int db = lane & 3;
    floatx4 o0 = {0,0,0,0}, o1 = {0,0,0,0}, o2 = {0,0,0,0}, o3 = {0,0,0,0};
    const float* Sh = &S4[wid][h * 17];
#pragma unroll
    for (int g = 0; g < 16; g++) {
        float p = Sh[g];
        const floatx4* Vg = (const floatx4*)(X + g * 204 + 128 + db * 16);
        o0 += Vg[0] * p;
        o1 += Vg[1] * p;
        o2 += Vg[2] * p;
        o3 += Vg[3] * p;
    }
    unsigned int w[8];
    w[0] = (unsigned)f2bf(o0[0]) | ((unsigned)f2bf(o0[1]) << 16);
    w[1] = (unsigned)f2bf(o0[2]) | ((unsigned)f2bf(o0[3]) << 16);
    w[2] = (unsigned)f2bf(o1[0]) | ((unsigned)f2bf(o1[1]) << 16);
    w[3] = (unsigned)f2bf(o1[2]) | ((unsigned)f2bf(o1[3]) << 16);
    w[4] = (unsigned)f2bf(o2[0]) | ((unsigned)f2bf(o2[1]) << 16);
    w[5] = (unsigned)f2bf(o2[2]) | ((unsigned)f2bf(o2[3]) << 16);
    w[6] = (unsigned)f2bf(o3[0]) | ((unsigned)f2bf(o3[1]) << 16);
    w[7] = (unsigned)f2bf(o3[2]) | ((unsigned)f2bf(o3[3]) << 16);
    uint4* dst = (uint4*)&aout[(size_t)t * DM + h * 64 + db * 16];
    dst[0] = make_uint4(w[0], w[1], w[2], w[3]);
    dst[1] = make_uint4(w[4], w[5], w[6], w[7]);
}

extern "C" void kernel_launch(void* const* d_in, const int* in_sizes, int n_in,
                              void* d_out, int out_size, void* d_ws, size_t ws_size,
                              hipStream_t stream) {
    const float* x     = (const float*)d_in[0];
    const float* w_qkv = (const float*)d_in[1];
    const float* b_qkv = (const float*)d_in[2];
    const float* w_out = (const float*)d_in[3];
    const float* b_out = (const float*)d_in[4];
    float* out = (float*)d_out;

    // ws layout (bytes):
    //   pe      fp32 [4096][64]        @ 0          (1 MiB)
    //   wqkvT   bf16 [3072][1024]      @ 1 MiB      (6 MiB)
    //   woutT   bf16 [1024][1024]      @ 7 MiB      (2 MiB)
    //   xbf     bf16 [32768][1024]     @ 9 MiB      (64 MiB)   (reused as attn_out)
    //   qkv     bf16 [32768][3072]     @ 73 MiB     (192 MiB)
    char* ws = (char*)d_ws;
    float*          pe    = (float*)ws;
    unsigned short* wqkvT = (unsigned short*)(ws + (1u << 20));
    unsigned short* woutT = (unsigned short*)(ws + (1u << 20) + 6291456u);
    unsigned short* xbf   = (unsigned short*)(ws + (1u << 20) + 6291456u + 2097152u);
    unsigned short* qkv   = (unsigned short*)(ws + (1u << 20) + 6291456u + 2097152u + 67108864u);
    unsigned short* aout  = xbf;  // x_bf16 dead after GEMM1; reuse for attention output

    // prep
    k_cast_bf16<<<(NTOK * DM / 4 + 255) / 256, 256, 0, stream>>>(x, xbf, NTOK * DM / 4);
    k_transpose_cast<1024, 3072><<<dim3(96, 32), dim3(32, 8), 0, stream>>>(w_qkv, wqkvT);
    k_transpose_cast<1024, 1024><<<dim3(32, 32), dim3(32, 8), 0, stream>>>(w_out, woutT);
    k_pe<<<512, 256, 0, stream>>>(pe);

    // qkv = x @ w_qkv + b_qkv  (fused: q*=1/8, k+=pe, bf16 store)
    k_gemm8<NQKV, 1><<<dim3((NQKV / 256) * (NTOK / 256)), 512, 0, stream>>>(xbf, wqkvT, b_qkv, pe, qkv);

    // per-token across-heads attention
    k_attn<<<NTOK / 4, 256, 0, stream>>>(qkv, aout);

    // out = attn_out @ w_out + b_out (fp32 store)
    k_gemm8<DM, 0><<<dim3((DM / 256) * (NTOK / 256)), 512, 0, stream>>>(aout, woutT, b_out, nullptr, out);
}